// Round 5
// baseline (3881.909 us; speedup 1.0000x reference)
//
#include <hip/hip_runtime.h>

typedef unsigned short u16;
typedef unsigned int u32;
typedef __attribute__((ext_vector_type(4))) float f32x4;
typedef __attribute__((ext_vector_type(8))) short s16x8;
typedef __attribute__((ext_vector_type(4))) int i32x4;

#define EPS 1e-5f

// ---------- helpers ----------
__device__ __forceinline__ u16 f2bf(float f) {
  unsigned u = __float_as_uint(f);
  return (u16)((u + 0x7fffu + ((u >> 16) & 1u)) >> 16);
}
__device__ __forceinline__ float sigm(float x) { return 1.0f / (1.0f + __expf(-x)); }
__device__ __forceinline__ float tanh_f(float x) {
  float e = __expf(-2.0f * fabsf(x));
  float r = (1.0f - e) / (1.0f + e);
  return copysignf(r, x);
}
__device__ __forceinline__ void gl_lds16(const void* g, void* l) {
  __builtin_amdgcn_global_load_lds(
      (const __attribute__((address_space(1))) u32*)g,
      (__attribute__((address_space(3))) u32*)l, 16, 0, 0);
}
__device__ __forceinline__ void bar_lgkm() {
  asm volatile("s_waitcnt lgkmcnt(0)" ::: "memory");
  __builtin_amdgcn_s_barrier();
  __builtin_amdgcn_sched_barrier(0);
}
__device__ __forceinline__ void bar_vm() {
  asm volatile("s_waitcnt vmcnt(0)" ::: "memory");
  __builtin_amdgcn_s_barrier();
  __builtin_amdgcn_sched_barrier(0);
}

// ---------- weight pack: conv_w (512,192,5) f32 -> per-fragment bf16 ----------
// f = (tap*6+kk)*32 + of ; of = 8*gate + chs ; element = lane*8+j
// A[o][c]: o = of*16 + (lane&15), c = kk*32 + (lane>>4)*8 + j
__global__ __launch_bounds__(256) void k_wcvt(const float* __restrict__ w, u16* __restrict__ Wpk) {
  int idx = blockIdx.x * 256 + threadIdx.x;   // exactly 491520 threads
  int f = idx >> 9, r = idx & 511;
  int lane = r >> 3, j = r & 7;
  int of = f & 31, tk = f >> 5;
  int kk = tk % 6, tap = tk / 6;
  int o = (of << 4) + (lane & 15);
  int c = (kk << 5) + ((lane >> 4) << 3) + j;
  Wpk[idx] = f2bf(w[(o * 192 + c) * 5 + tap]);
}

// ---------- x transpose: inputs (t,b,64,256) f32 -> xT[t*32+b][264 rows][64 c] bf16, swizzled ----------
__global__ __launch_bounds__(256) void k_xtrans(const float* __restrict__ x, u16* __restrict__ xT) {
  int tb = blockIdx.x;
  int tid = threadIdx.x;
  __shared__ __align__(16) u16 ltile[256 * 72];
  const float* src = x + tb * (64 * 256);
  for (int it = 0; it < 64; ++it) {
    int idx = it * 256 + tid;
    int c = idx >> 8, l = idx & 255;
    ltile[l * 72 + c] = f2bf(src[idx]);
  }
  __syncthreads();
  char* dst = (char*)(xT + tb * 16896);   // 264*64 u16 = 33792 B
  i32x4 z = {0, 0, 0, 0};
  for (int i = tid; i < 2112; i += 256) { // 264 rows * 8 chunks
    int r = i >> 3, ch = i & 7;
    i32x4 v = z;
    if (r >= 2 && r < 258) v = *(const i32x4*)(ltile + (r - 2) * 72 + ch * 8);
    *(i32x4*)(dst + r * 128 + ((ch * 16) ^ ((r & 7) << 4))) = v;
  }
}

// ---------- zero h-state (both buffers) + epoch flags ----------
__global__ void k_init(i32x4* __restrict__ hT, i32x4* __restrict__ ep) {
  int n = gridDim.x * blockDim.x;
  int tid = blockIdx.x * blockDim.x + threadIdx.x;
  i32x4 z = {0, 0, 0, 0};
  for (int i = tid; i < 270336; i += n) hT[i] = z;   // 2 x 32*264*128 u16
  for (int i = tid; i < 4096;   i += n) ep[i] = z;   // epS + epH (2 x 32KB)
}

// ---------- mega kernel: all 32 steps, group-scoped sync ----------
// grid 256: bid = chs*32 + b  (group = 8 blocks sharing b; same XCD under %8 round-robin)
// block 512 = 8 waves = ks(2 K-halves) x wcol(4 L-quarters); block tile 64 gate-M x 256 L
__global__ __launch_bounds__(512, 2) void k_mega(
    const u16* __restrict__ Wpk, const u16* __restrict__ xT, u16* __restrict__ hT,
    const float* __restrict__ cb, const float* __restrict__ gnw, const float* __restrict__ gnb,
    float* __restrict__ out, float* __restrict__ stats,
    int* __restrict__ epS, int* __restrict__ epH) {
  const int bid = blockIdx.x;
  const int b = bid & 31, chs = bid >> 5;
  const int tid = threadIdx.x;
  const int wave = tid >> 6, lane = tid & 63;
  const int ks = wave >> 2, wcol = wave & 3;
  const int cgrp = (lane >> 4) << 4;
  const int ch16 = (lane >> 4) << 2;
  const int l15 = lane & 15;

  __shared__ __align__(16) char ldsx[33792];   // 264 rows x 128 B (x, swizzled)
  __shared__ __align__(16) char ldsh[67584];   // 264 rows x 256 B (h, swizzled); reused for acc-exchange
  __shared__ __align__(16) char hl[8192];      // 256 L x 32 B (16 ch bf16)
  __shared__ float red[8][4][2];
  __shared__ float smu[4], srs[4];

  // step-invariant per-thread params (kept channels: chs*16 + ch16 + r)
  f32x4 biasv[4], wgn[4], bgn[4];
  #pragma unroll
  for (int g = 0; g < 4; ++g) {
    biasv[g] = *(const f32x4*)(cb  + (g << 7) + (chs << 4) + ch16);
    wgn[g]   = *(const f32x4*)(gnw + (g << 7) + (chs << 4) + ch16);
    bgn[g]   = *(const f32x4*)(gnb + (g << 7) + (chs << 4) + ch16);
  }
  float cxr[2][4];
  #pragma unroll
  for (int q = 0; q < 2; ++q)
    #pragma unroll
    for (int r = 0; r < 4; ++r) cxr[q][r] = 0.f;

  // ---- prologue: stage x(0) ----
  {
    const char* xs = (const char*)(xT + b * 16896);
    for (int i = tid; i < 2112; i += 512) gl_lds16(xs + (i << 4), ldsx + ((i >> 6) << 10));
  }
  asm volatile("s_waitcnt vmcnt(0)" ::: "memory");
  __syncthreads();

  #pragma unroll 1
  for (int t = 0; t < 32; ++t) {
    f32x4 zero4 = {0.f, 0.f, 0.f, 0.f};
    f32x4 acc[4][4];
    #pragma unroll
    for (int g = 0; g < 4; ++g)
      #pragma unroll
      for (int ni = 0; ni < 4; ++ni) acc[g][ni] = zero4;

    // ---- phase 1: 5 x-chunks (h not needed) ----
    #pragma unroll
    for (int i = 0; i < 5; ++i) {
      const int j = ks * 5 + i;
      const int tap = j >> 1, kk = j & 1;
      const int cc = tap * 6 + kk;
      s16x8 av[4], bv[4];
      #pragma unroll
      for (int g = 0; g < 4; ++g)
        av[g] = *(const s16x8*)((const char*)Wpk + (((cc << 5) + (g << 3) + chs) << 10) + (lane << 4));
      #pragma unroll
      for (int ni = 0; ni < 4; ++ni) {
        const int row = (wcol << 6) + (ni << 4) + l15 + tap;
        const int sw = (row & 7) << 4;
        bv[ni] = *(const s16x8*)(ldsx + (row << 7) + (((kk << 6) + cgrp) ^ sw));
      }
      #pragma unroll
      for (int g = 0; g < 4; ++g)
        #pragma unroll
        for (int ni = 0; ni < 4; ++ni)
          acc[g][ni] = __builtin_amdgcn_mfma_f32_16x16x32_bf16(av[g], bv[ni], acc[g][ni], 0, 0, 0);
    }

    // ---- group h-barrier (relaxed polls, one acquire fence) + stage h(t) ----
    if (tid < 8) {
      const int midx = ((tid << 5) + b) << 5;     // member bid = tid*32+b, stride 32 ints
      while (__hip_atomic_load(epH + midx, __ATOMIC_RELAXED, __HIP_MEMORY_SCOPE_AGENT) < t)
        __builtin_amdgcn_s_sleep(2);
    }
    __syncthreads();
    if (tid == 0) __builtin_amdgcn_fence(__ATOMIC_ACQUIRE, "agent");
    __syncthreads();
    {
      const char* hs = (const char*)hT + (t & 1) * 2162688 + b * 67584;
      for (int i = tid; i < 4224; i += 512) gl_lds16(hs + (i << 4), ldsh + ((i >> 6) << 10));
    }
    bar_vm();

    // ---- phase 2: 10 h-chunks ----
    #pragma unroll
    for (int i = 0; i < 10; ++i) {
      const int j = ks * 10 + i;
      const int tap = j >> 2, kk2 = j & 3;
      const int cc = tap * 6 + kk2 + 2;
      s16x8 av[4], bv[4];
      #pragma unroll
      for (int g = 0; g < 4; ++g)
        av[g] = *(const s16x8*)((const char*)Wpk + (((cc << 5) + (g << 3) + chs) << 10) + (lane << 4));
      #pragma unroll
      for (int ni = 0; ni < 4; ++ni) {
        const int row = (wcol << 6) + (ni << 4) + l15 + tap;
        const int sw = (row & 7) << 4;
        bv[ni] = *(const s16x8*)(ldsh + (row << 8) + (((kk2 << 6) + cgrp) ^ sw));
      }
      #pragma unroll
      for (int g = 0; g < 4; ++g)
        #pragma unroll
        for (int ni = 0; ni < 4; ++ni)
          acc[g][ni] = __builtin_amdgcn_mfma_f32_16x16x32_bf16(av[g], bv[ni], acc[g][ni], 0, 0, 0);
    }
    bar_lgkm();   // (A) all waves done reading ldsx/ldsh

    // ---- symmetric K-split exchange via ldsh; prefetch x(t+1) into ldsx ----
    #pragma unroll
    for (int g = 0; g < 4; ++g)
      #pragma unroll
      for (int q = 0; q < 2; ++q)
        *(f32x4*)(ldsh + (wave << 13) + (((g << 1) + q) << 10) + (lane << 4)) =
            acc[g][((1 - ks) << 1) + q];
    if (t < 31) {
      const char* xs = (const char*)(xT + (((t + 1) << 5) + b) * 16896);
      for (int i = tid; i < 2112; i += 512) gl_lds16(xs + (i << 4), ldsx + ((i >> 6) << 10));
    }
    bar_lgkm();   // (B)

    // ---- merge partner partials; +bias; per-gate partial stats ----
    float sum[4], sq[4];
    const int pw = wave ^ 4;
    #pragma unroll
    for (int g = 0; g < 4; ++g) {
      sum[g] = 0.f; sq[g] = 0.f;
      #pragma unroll
      for (int q = 0; q < 2; ++q) {
        const int ni = (ks << 1) + q;
        f32x4 v = *(const f32x4*)(ldsh + (pw << 13) + (((g << 1) + q) << 10) + (lane << 4));
        #pragma unroll
        for (int r = 0; r < 4; ++r) {
          float x = v[r] + acc[g][ni][r] + biasv[g][r];
          v[r] = x; sum[g] += x; sq[g] += x * x;
        }
        acc[g][ni] = v;
      }
    }
    #pragma unroll
    for (int off = 1; off < 64; off <<= 1) {
      #pragma unroll
      for (int g = 0; g < 4; ++g) {
        sum[g] += __shfl_xor(sum[g], off);
        sq[g]  += __shfl_xor(sq[g], off);
      }
    }
    if (lane == 0) {
      #pragma unroll
      for (int g = 0; g < 4; ++g) { red[wave][g][0] = sum[g]; red[wave][g][1] = sq[g]; }
    }
    bar_lgkm();   // (C)

    // ---- pair stats exchange (partner = bid^32), relaxed polls + one fence ----
    if (tid == 0) {
      float s4[4], q4[4];
      #pragma unroll
      for (int g = 0; g < 4; ++g) {
        float s = 0.f, q = 0.f;
        #pragma unroll
        for (int w = 0; w < 8; ++w) { s += red[w][g][0]; q += red[w][g][1]; }
        s4[g] = s; q4[g] = q;
      }
      float* so = stats + (bid << 5);
      #pragma unroll
      for (int g = 0; g < 4; ++g) {
        __hip_atomic_store(so + (g << 1),     s4[g], __ATOMIC_RELAXED, __HIP_MEMORY_SCOPE_AGENT);
        __hip_atomic_store(so + (g << 1) + 1, q4[g], __ATOMIC_RELAXED, __HIP_MEMORY_SCOPE_AGENT);
      }
      __hip_atomic_store(epS + (bid << 5), t + 1, __ATOMIC_RELEASE, __HIP_MEMORY_SCOPE_AGENT);
      while (__hip_atomic_load(epS + ((bid ^ 32) << 5), __ATOMIC_RELAXED, __HIP_MEMORY_SCOPE_AGENT) <= t)
        __builtin_amdgcn_s_sleep(2);
      __builtin_amdgcn_fence(__ATOMIC_ACQUIRE, "agent");
      const float* pe = stats + ((bid & ~32) << 5);   // fixed even+odd order -> identical in pair
      const float* po = stats + ((bid | 32)  << 5);
      const float inv = 1.0f / 8192.0f;
      #pragma unroll
      for (int g = 0; g < 4; ++g) {
        float s = __hip_atomic_load(pe + (g << 1), __ATOMIC_RELAXED, __HIP_MEMORY_SCOPE_AGENT)
                + __hip_atomic_load(po + (g << 1), __ATOMIC_RELAXED, __HIP_MEMORY_SCOPE_AGENT);
        float q = __hip_atomic_load(pe + (g << 1) + 1, __ATOMIC_RELAXED, __HIP_MEMORY_SCOPE_AGENT)
                + __hip_atomic_load(po + (g << 1) + 1, __ATOMIC_RELAXED, __HIP_MEMORY_SCOPE_AGENT);
        float m = s * inv;
        smu[g] = m;
        srs[g] = rsqrtf(q * inv - m * m + EPS);
      }
    }
    bar_lgkm();   // (E)

    // ---- GN apply + LSTM pointwise; cx in registers ----
    const float mu0 = smu[0], mu1 = smu[1], mu2 = smu[2], mu3 = smu[3];
    const float rs0 = srs[0], rs1 = srs[1], rs2 = srs[2], rs3 = srs[3];
    float* outp = out + (((t << 5) + b) << 15);
    #pragma unroll
    for (int q = 0; q < 2; ++q) {
      const int ni = (ks << 1) + q;
      const int l = (wcol << 6) + (ni << 4) + l15;
      u16 hp[4];
      #pragma unroll
      for (int r = 0; r < 4; ++r) {
        const int c = (chs << 4) + ch16 + r;   // hy channel
        float vi = (acc[0][ni][r] - mu0) * rs0 * wgn[0][r] + bgn[0][r];
        float vf = (acc[1][ni][r] - mu1) * rs1 * wgn[1][r] + bgn[1][r];
        float vg = (acc[2][ni][r] - mu2) * rs2 * wgn[2][r] + bgn[2][r];
        float vo = (acc[3][ni][r] - mu3) * rs3 * wgn[3][r] + bgn[3][r];
        float cyv = sigm(vf) * cxr[q][r] + sigm(vi) * tanh_f(vg);
        float hyv = sigm(vo) * tanh_f(cyv);
        cxr[q][r] = cyv;
        outp[(c << 8) + l] = hyv;
        hp[r] = f2bf(hyv);
        if (t == 31) {
          const int cxi = (((b << 7) + c) << 8) + l;
          out[33554432 + cxi] = hyv;   // final hy
          out[34603008 + cxi] = cyv;   // final cy
        }
      }
      *(unsigned long long*)(hl + (l << 5) + ((ch16 << 1) ^ ((l & 1) << 4))) =
          *(const unsigned long long*)hp;
    }
    bar_lgkm();   // (F)

    // ---- transposed h write + release epoch ----
    if (t < 31) {
      u16* hTw = hT + ((t + 1) & 1) * 1081344;
      const int l = tid >> 1, k = tid & 1;
      const int row = l + 2;
      i32x4 v = *(const i32x4*)(hl + (l << 5) + ((k << 4) ^ ((l & 1) << 4)));
      *(i32x4*)((char*)hTw + b * 67584 + (row << 8) +
                ((((chs << 1) + k) << 4) ^ ((row & 7) << 4))) = v;
      __syncthreads();   // drain every thread's stores (incl. x-prefetch) before release
      if (tid == 0)
        __hip_atomic_store(epH + (bid << 5), t + 1, __ATOMIC_RELEASE, __HIP_MEMORY_SCOPE_AGENT);
    }
  }
}

// ---------- launch ----------
extern "C" void kernel_launch(void* const* d_in, const int* in_sizes, int n_in,
                              void* d_out, int out_size, void* d_ws, size_t ws_size,
                              hipStream_t stream) {
  const float* x  = (const float*)d_in[0];
  const float* cw = (const float*)d_in[1];
  const float* cb = (const float*)d_in[2];
  const float* gw = (const float*)d_in[3];
  const float* gb = (const float*)d_in[4];
  float* out = (float*)d_out;
  char* ws = (char*)d_ws;

  u16*   Wpk   = (u16*)(ws);                 //     983,040 B
  u16*   xT    = (u16*)(ws + 983040);        //  34,603,008 B
  u16*   hT    = (u16*)(ws + 35586048);      //   4,325,376 B (ping-pong)
  float* stats = (float*)(ws + 39911424);    //      32,768 B (128B-padded per bid)
  int*   epS   = (int*)(ws + 39944192);      //      32,768 B
  int*   epH   = (int*)(ws + 39976960);      //      32,768 B  (~40.0 MB)

  k_wcvt<<<1920, 256, 0, stream>>>(cw, Wpk);
  k_xtrans<<<1024, 256, 0, stream>>>(x, xT);
  k_init<<<256, 256, 0, stream>>>((i32x4*)hT, (i32x4*)epS);
  k_mega<<<256, 512, 0, stream>>>(Wpk, xT, hT, cb, gw, gb, out, stats, epS, epH);
}

// Round 6
// 1004.970 us; speedup vs baseline: 3.8627x; 3.8627x over previous
//
#include <hip/hip_runtime.h>

typedef unsigned short u16;
typedef unsigned int u32;
typedef __attribute__((ext_vector_type(4))) float f32x4;
typedef __attribute__((ext_vector_type(8))) short s16x8;
typedef __attribute__((ext_vector_type(4))) int i32x4;

#define EPS 1e-5f

// ---------- helpers ----------
__device__ __forceinline__ u16 f2bf(float f) {
  unsigned u = __float_as_uint(f);
  return (u16)((u + 0x7fffu + ((u >> 16) & 1u)) >> 16);
}
__device__ __forceinline__ float sigm(float x) { return 1.0f / (1.0f + __expf(-x)); }
__device__ __forceinline__ float tanh_f(float x) {
  float e = __expf(-2.0f * fabsf(x));
  float r = (1.0f - e) / (1.0f + e);
  return copysignf(r, x);
}
__device__ __forceinline__ void gl_lds16(const void* g, void* l) {
  __builtin_amdgcn_global_load_lds(
      (const __attribute__((address_space(1))) u32*)g,
      (__attribute__((address_space(3))) u32*)l, 16, 0, 0);
}

// ---------- weight pack: conv_w (512,192,5) f32 -> per-fragment bf16 ----------
// f = (tap*6+kk)*32 + of ; of = o>>4 (o = gate-ch/16) ; element = lane*8+j
// A[o][c]: o = of*16 + (lane&15), c = kk*32 + (lane>>4)*8 + j
__global__ __launch_bounds__(256) void k_wcvt(const float* __restrict__ w, u16* __restrict__ Wpk) {
  int idx = blockIdx.x * 256 + threadIdx.x;   // exactly 491520 threads
  int f = idx >> 9, r = idx & 511;
  int lane = r >> 3, j = r & 7;
  int of = f & 31, tk = f >> 5;
  int kk = tk % 6, tap = tk / 6;
  int o = (of << 4) + (lane & 15);
  int c = (kk << 5) + ((lane >> 4) << 3) + j;
  Wpk[idx] = f2bf(w[(o * 192 + c) * 5 + tap]);
}

// ---------- x transpose: inputs (t,b,64,256) f32 -> xT[t*32+b][264 rows][64 c] bf16, swizzled ----------
__global__ __launch_bounds__(256) void k_xtrans(const float* __restrict__ x, u16* __restrict__ xT) {
  int tb = blockIdx.x;
  int tid = threadIdx.x;
  __shared__ __align__(16) u16 ltile[256 * 72];
  const float* src = x + tb * (64 * 256);
  for (int it = 0; it < 64; ++it) {
    int idx = it * 256 + tid;
    int c = idx >> 8, l = idx & 255;
    ltile[l * 72 + c] = f2bf(src[idx]);
  }
  __syncthreads();
  char* dst = (char*)(xT + tb * 16896);   // 264*64 u16 = 33792 B
  i32x4 z = {0, 0, 0, 0};
  for (int i = tid; i < 2112; i += 256) { // 264 rows * 8 chunks
    int r = i >> 3, ch = i & 7;
    i32x4 v = z;
    if (r >= 2 && r < 258) v = *(const i32x4*)(ltile + (r - 2) * 72 + ch * 8);
    *(i32x4*)(dst + r * 128 + ((ch * 16) ^ ((r & 7) << 4))) = v;
  }
}

// ---------- zero h-state + c-state + stats ----------
__global__ void k_init(i32x4* __restrict__ hT, i32x4* __restrict__ cxv, i32x4* __restrict__ st) {
  int n = gridDim.x * blockDim.x;
  int tid = blockIdx.x * blockDim.x + threadIdx.x;
  i32x4 z = {0, 0, 0, 0};
  for (int i = tid; i < 135168; i += n) hT[i] = z;   // 32*264*128 u16
  for (int i = tid; i < 262144; i += n) cxv[i] = z;  // 32*128*256 f32
  for (int i = tid; i < 8192;   i += n) st[i] = z;   // 32*32*16*2 f32
}

// ---------- conv + bias + gates + GN partial stats ----------
// grid 256: bid = ((mh*2+lh)*4 + b>>3)*8 + (b&7)  (1 block/CU; b -> XCD b%8)
// block 256 thr = 4 waves (wm 2 x wl 2); block tile M=128 (gate mh) x N=128 L; wave 64x64
__global__ __launch_bounds__(256, 1) void k_conv(
    const u16* __restrict__ Wpk, const u16* __restrict__ xT, const u16* __restrict__ hT,
    const float* __restrict__ cb, float* __restrict__ gates, float* __restrict__ stats, int t) {
  const int bid = blockIdx.x;
  const int b = (((bid >> 3) & 3) << 3) | (bid & 7);
  const int lh = (bid >> 5) & 1;
  const int mh = bid >> 6;                    // gate index 0..3
  const int tid = threadIdx.x, wave = tid >> 6, lane = tid & 63;
  const int wm = wave & 1, wl = wave >> 1;
  const int cgrp = (lane >> 4) << 4;
  const int l15 = lane & 15;

  __shared__ __align__(16) char ldsx[16896];  // 132 rows x 128 B (x, swizzled)
  __shared__ __align__(16) char ldsh[33792];  // 132 rows x 256 B (h, swizzled)
  __shared__ float red[4][2][2];

  // ---- stage B tiles (swizzle pre-baked in global) ----
  {
    const char* gx = (const char*)(xT + ((t << 5) + b) * 16896) + (lh << 14);
    for (int i = tid; i < 1056; i += 256) gl_lds16(gx + (i << 4), ldsx + (i << 4));
    const char* gh = (const char*)hT + b * 67584 + (lh << 15);
    for (int i = tid; i < 2112; i += 256) gl_lds16(gh + (i << 4), ldsh + (i << 4));
  }
  asm volatile("s_waitcnt vmcnt(0)" ::: "memory");
  __syncthreads();

  // ---- K-loop: 30 chunks, A direct from global (L2), B from LDS, no barriers ----
  f32x4 zero4 = {0.f, 0.f, 0.f, 0.f};
  f32x4 acc[4][4];
  #pragma unroll
  for (int mi = 0; mi < 4; ++mi)
    #pragma unroll
    for (int ni = 0; ni < 4; ++ni) acc[mi][ni] = zero4;

  const s16x8* Wv = (const s16x8*)Wpk;
  const int afb = (mh << 3) + (wm << 2);      // A-frag base within chunk

  #pragma unroll
  for (int cc = 0; cc < 30; ++cc) {
    const int tap = cc / 6, kk = cc % 6;
    s16x8 av[4], bv[4];
    #pragma unroll
    for (int mi = 0; mi < 4; ++mi)
      av[mi] = Wv[(((cc << 5) + afb + mi) << 6) + lane];
    #pragma unroll
    for (int ni = 0; ni < 4; ++ni) {
      const int row = (wl << 6) + (ni << 4) + l15 + tap;
      const int sw = (row & 7) << 4;
      bv[ni] = (kk < 2)
        ? *(const s16x8*)(ldsx + (row << 7) + (((kk << 6) + cgrp) ^ sw))
        : *(const s16x8*)(ldsh + (row << 8) + ((((kk - 2) << 6) + cgrp) ^ sw));
    }
    #pragma unroll
    for (int mi = 0; mi < 4; ++mi)
      #pragma unroll
      for (int ni = 0; ni < 4; ++ni)
        acc[mi][ni] = __builtin_amdgcn_mfma_f32_16x16x32_bf16(av[mi], bv[ni], acc[mi][ni], 0, 0, 0);
  }

  // ---- epilogue: +bias, write f32 gates, per-group partial stats ----
  const int ch4 = (lane >> 4) << 2;           // ch quarter within 16
  float sum[2] = {0.f, 0.f}, sq[2] = {0.f, 0.f};
  #pragma unroll
  for (int mi = 0; mi < 4; ++mi) {
    const int gc0 = (mh << 7) + (wm << 6) + (mi << 4) + ch4;   // gate-ch for r=0
    const f32x4 bias = *(const f32x4*)(cb + gc0);
    const int gi = mi >> 1;
    #pragma unroll
    for (int ni = 0; ni < 4; ++ni) {
      const int l = (lh << 7) + (wl << 6) + (ni << 4) + l15;
      #pragma unroll
      for (int r = 0; r < 4; ++r) {
        float v = acc[mi][ni][r] + bias[r];
        gates[(((b << 9) + gc0 + r) << 8) + l] = v;
        sum[gi] += v; sq[gi] += v * v;
      }
    }
  }
  #pragma unroll
  for (int off = 1; off < 64; off <<= 1) {
    sum[0] += __shfl_xor(sum[0], off); sq[0] += __shfl_xor(sq[0], off);
    sum[1] += __shfl_xor(sum[1], off); sq[1] += __shfl_xor(sq[1], off);
  }
  if (lane == 0) {
    red[wave][0][0] = sum[0]; red[wave][0][1] = sq[0];
    red[wave][1][0] = sum[1]; red[wave][1][1] = sq[1];
  }
  __syncthreads();
  if (tid < 8) {   // 2 contributors (lh) per counter -> commutative -> deterministic
    const int wm2 = tid >> 2, gi = (tid >> 1) & 1, j = tid & 1;
    float v = red[wm2][gi][j] + red[wm2 + 2][gi][j];
    const int grp = (mh << 2) + (wm2 << 1) + gi;
    atomicAdd(&stats[(((t << 5) + b) << 5) + (grp << 1) + j], v);
  }
}

// ---------- GN apply + LSTM pointwise + swizzled transposed h write ----------
// grid 256: bid = ((cs*2+lh)*4 + b>>3)*8 + (b&7); block 256 thr, no LDS
__global__ __launch_bounds__(256) void k_point(
    const float* __restrict__ gates, const float* __restrict__ stats,
    const float* __restrict__ gnw, const float* __restrict__ gnb,
    float* __restrict__ cx, u16* __restrict__ hT, float* __restrict__ out, int t) {
  const int bid = blockIdx.x;
  const int b = (((bid >> 3) & 3) << 3) | (bid & 7);
  const int lh = (bid >> 5) & 1;
  const int cs = bid >> 6;                    // 32-ch strip 0..3
  const int tid = threadIdx.x;

  const float inv = 1.0f / 8192.0f;
  const float* st = stats + (((t << 5) + b) << 5);
  float mu[4], rs[4];
  #pragma unroll
  for (int g = 0; g < 4; ++g) {
    const int grp = (g << 2) + cs;
    float s = st[grp << 1], q = st[(grp << 1) + 1];
    float m = s * inv;
    mu[g] = m;
    rs[g] = rsqrtf(q * inv - m * m + EPS);
  }

  const int lr = tid & 127;
  const int l = (lh << 7) + lr;
  float* outp = out + (((t << 5) + b) << 15);

  #pragma unroll
  for (int k2 = 0; k2 < 2; ++k2) {
    const int kq = (tid >> 7) + (k2 << 1);    // octet index 0..3
    const int c8 = (cs << 5) + (kq << 3);     // first hy-ch of octet
    s16x8 hp;
    #pragma unroll
    for (int r = 0; r < 8; ++r) {
      const int c = c8 + r;
      const int base = (((b << 9) + c) << 8) + l;
      float vi = gates[base];
      float vf = gates[base + (1 << 15)];
      float vg = gates[base + (2 << 15)];
      float vo = gates[base + (3 << 15)];
      vi = (vi - mu[0]) * rs[0] * gnw[c]       + gnb[c];
      vf = (vf - mu[1]) * rs[1] * gnw[c + 128] + gnb[c + 128];
      vg = (vg - mu[2]) * rs[2] * gnw[c + 256] + gnb[c + 256];
      vo = (vo - mu[3]) * rs[3] * gnw[c + 384] + gnb[c + 384];
      const int cxi = (((b << 7) + c) << 8) + l;
      float cyv = sigm(vf) * cx[cxi] + sigm(vi) * tanh_f(vg);
      float hyv = sigm(vo) * tanh_f(cyv);
      cx[cxi] = cyv;
      outp[(c << 8) + l] = hyv;
      hp[r] = (short)f2bf(hyv);
      if (t == 31) {
        out[33554432 + cxi] = hyv;   // final hy
        out[34603008 + cxi] = cyv;   // final cy
      }
    }
    // one 16B granule store in hT's swizzled layout (row = l+2, granule = cs*4+kq)
    const int row = l + 2;
    char* dst = (char*)hT + b * 67584 + (row << 8) +
                ((((cs << 2) + kq) << 4) ^ ((row & 7) << 4));
    *(i32x4*)dst = *(const i32x4*)&hp;
  }
}

// ---------- launch ----------
extern "C" void kernel_launch(void* const* d_in, const int* in_sizes, int n_in,
                              void* d_out, int out_size, void* d_ws, size_t ws_size,
                              hipStream_t stream) {
  const float* x  = (const float*)d_in[0];
  const float* cw = (const float*)d_in[1];
  const float* cb = (const float*)d_in[2];
  const float* gw = (const float*)d_in[3];
  const float* gb = (const float*)d_in[4];
  float* out = (float*)d_out;
  char* ws = (char*)d_ws;

  u16*   Wpk   = (u16*)(ws);                 //     983,040 B
  u16*   xT    = (u16*)(ws + 983040);        //  34,603,008 B
  u16*   hT    = (u16*)(ws + 35586048);      //   2,162,688 B
  float* cx    = (float*)(ws + 37748736);    //   4,194,304 B
  float* gates = (float*)(ws + 41943040);    //  16,777,216 B
  float* stats = (float*)(ws + 58720256);    //     131,072 B  (~56.1 MB)

  k_wcvt<<<1920, 256, 0, stream>>>(cw, Wpk);
  k_xtrans<<<1024, 256, 0, stream>>>(x, xT);
  k_init<<<512, 256, 0, stream>>>((i32x4*)hT, (i32x4*)cx, (i32x4*)stats);
  for (int t = 0; t < 32; ++t) {
    k_conv<<<256, 256, 0, stream>>>(Wpk, xT, hT, cb, gates, stats, t);
    k_point<<<256, 256, 0, stream>>>(gates, stats, gw, gb, cx, hT, out, t);
  }
}